// Round 15
// baseline (196.568 us; speedup 1.0000x reference)
//
#include <hip/hip_runtime.h>
#include <cstdint>

#define NB    8
#define NSEQ  4096
#define CDIM  256
#define NTOK  (NB*NSEQ)

typedef _Float16 half8  __attribute__((ext_vector_type(8)));
typedef _Float16 half4v __attribute__((ext_vector_type(4)));
typedef float    f32x4  __attribute__((ext_vector_type(4)));
typedef float    f32x16 __attribute__((ext_vector_type(16)));
typedef uint32_t u32x4  __attribute__((ext_vector_type(4)));
typedef unsigned long u64x2 __attribute__((ext_vector_type(2)));

typedef unsigned int u32_g __attribute__((address_space(1)));
typedef unsigned int u32_l __attribute__((address_space(3)));

// direct global->LDS, 16B per lane; LDS dest = wave-uniform base + lane*16
__device__ __forceinline__ void gload_lds16(const void* g, void* l) {
  __builtin_amdgcn_global_load_lds((u32_g*)(uintptr_t)g,
                                   (u32_l*)(uint32_t)(uintptr_t)l, 16, 0, 0);
}

__device__ __forceinline__ uint8_t to_fp8(float v) {
  return (uint8_t)(__builtin_amdgcn_cvt_pk_fp8_f32(v, v, 0, false) & 0xff);
}
// pack 4 floats -> 4 fp8 bytes in one u32
__device__ __forceinline__ uint32_t pk4_fp8(float a, float b, float c, float d) {
  uint32_t w = (uint32_t)__builtin_amdgcn_cvt_pk_fp8_f32(a, b, 0, false);
  return (uint32_t)__builtin_amdgcn_cvt_pk_fp8_f32(c, d, (int)w, true);
}
// lane^32 exchange via shfl (semantics-certain)
__device__ __forceinline__ float sx32f(float v) { return __shfl_xor(v, 32, 64); }
__device__ __forceinline__ uint32_t sx32u(uint32_t v) {
  return (uint32_t)__shfl_xor((int)v, 32, 64);
}

// ---------------- LayerNorm: one wave per token; f16 xn only
__global__ __launch_bounds__(256) void ln_kernel(
    const float* __restrict__ x, const float* __restrict__ gam,
    const float* __restrict__ bet, _Float16* __restrict__ xnh) {
  const int lane = threadIdx.x & 63;
  const size_t tok = (size_t)blockIdx.x * 4 + (threadIdx.x >> 6);
  const float4 v = ((const float4*)(x + tok * CDIM))[lane];
  float s  = v.x + v.y + v.z + v.w;
  float s2 = v.x*v.x + v.y*v.y + v.z*v.z + v.w*v.w;
  #pragma unroll
  for (int m = 1; m < 64; m <<= 1) {
    s  += __shfl_xor(s,  m, 64);
    s2 += __shfl_xor(s2, m, 64);
  }
  const float mean = s * (1.0f / CDIM);
  const float rstd = rsqrtf(s2 * (1.0f / CDIM) - mean * mean + 1e-3f);
  const float4 gv = ((const float4*)gam)[lane];
  const float4 bv = ((const float4*)bet)[lane];
  half4v h;
  h[0] = (_Float16)((v.x - mean) * rstd * gv.x + bv.x);
  h[1] = (_Float16)((v.y - mean) * rstd * gv.y + bv.y);
  h[2] = (_Float16)((v.z - mean) * rstd * gv.z + bv.z);
  h[3] = (_Float16)((v.w - mean) * rstd * gv.w + bv.w);
  ((half4v*)(xnh + tok * CDIM))[lane] = h;
}

// ---------------- projection GEMM
// modes: 0=Q (fp8, log2e folded), 1=K (fp8), 2=V (fp8 chunked [b][nblk][512slot][16B]),
//        3=P (fp32 + residual).
// Q/K fp8 rows hi-split: byte(m,hi,j) = (m>>1)*32 + hi*16 + (m&1)*8 + j.
// V chunk layout: slot(d,sel) = (d>>3)*16 + sel*8 + (d&7); chunk bytes:
//   sel=0 = [kv0-7 | kv16-23], sel=1 = [kv8-15 | kv24-31] (kv = token & 31).
__global__ __launch_bounds__(256, 2) void proj_kernel(
    const _Float16* __restrict__ inh,
    const float* __restrict__ wq_, const float* __restrict__ bq_,
    const float* __restrict__ wk_, const float* __restrict__ bk_,
    const float* __restrict__ wv_, const float* __restrict__ bv_,
    const float* __restrict__ wp_, const float* __restrict__ bp_,
    uint8_t* __restrict__ qg8, uint8_t* __restrict__ kg8,
    uint8_t* __restrict__ vt8,
    const _Float16* __restrict__ residh, float* __restrict__ outf,
    int mode_base) {
  extern __shared__ char smem[];
  const int mode = mode_base + blockIdx.z;
  const float* wsel = (mode == 0) ? wq_ : (mode == 1) ? wk_ : (mode == 2) ? wv_ : wp_;
  const float* bsel = (mode == 0) ? bq_ : (mode == 1) ? bk_ : (mode == 2) ? bv_ : bp_;

  const int tid = threadIdx.x;
  const int lane = tid & 63;
  const int wid  = tid >> 6;     // 0..3
  const int g    = lane >> 4;    // 0..3
  const int lr   = lane & 15;
  const int jstrip = blockIdx.y; // 0..3
  const size_t tok0 = (size_t)blockIdx.x * 512;

  char* wt   = smem;             // [64 j][256 c] f16, XOR-swizzled (32KB)
  char* tile = smem + 32768;     // [64 tok][256 c] f16, swizzled (32KB)

  for (int i = 0; i < 64; ++i) {
    int idx = i * 256 + tid;
    int c = idx >> 6, j = idx & 63;
    float val = wsel[(size_t)c * CDIM + jstrip * 64 + j];
    *(_Float16*)(wt + j * 512 + ((((c >> 3) ^ (j & 7))) << 4) + ((c & 7) << 1)) =
        (_Float16)val;
  }
  float bjv[4];
  #pragma unroll
  for (int jc = 0; jc < 4; ++jc) bjv[jc] = bsel[jstrip * 64 + jc * 16 + lr];
  __syncthreads();

  for (int t = 0; t < 8; ++t) {
    const size_t trow0 = tok0 + t * 64;
    #pragma unroll
    for (int i = 0; i < 8; ++i) {
      int pbase = (i * 4 + wid) * 64;
      int p = pbase + lane;
      int row = p >> 5, sl = p & 31;
      gload_lds16(inh + (trow0 + row) * CDIM + (size_t)((sl ^ (row & 7)) * 8),
                  tile + pbase * 16);
    }
    __syncthreads();

    f32x4 acc[4] = {{0,0,0,0},{0,0,0,0},{0,0,0,0},{0,0,0,0}};
    #pragma unroll
    for (int kc = 0; kc < 8; ++kc) {
      half8 a = *(const half8*)(tile + (wid * 16 + lr) * 512 +
                                ((((kc << 2) | g) ^ (lr & 7)) << 4));
      #pragma unroll
      for (int jc = 0; jc < 4; ++jc) {
        half8 bf = *(const half8*)(wt + (jc * 16 + lr) * 512 +
                                   ((((kc << 2) | g) ^ (lr & 7)) << 4));
        acc[jc] = __builtin_amdgcn_mfma_f32_16x16x32_f16(a, bf, acc[jc], 0, 0, 0);
      }
    }

    if (mode == 3) {
      #pragma unroll
      for (int jc = 0; jc < 4; ++jc) {
        #pragma unroll
        for (int r = 0; r < 4; ++r) {
          size_t row = trow0 + wid * 16 + g * 4 + r;
          size_t off = row * CDIM + jstrip * 64 + jc * 16 + lr;
          outf[off] = acc[jc][r] + bjv[jc] + (float)residh[off];
        }
      }
    } else if (mode <= 1) {
      // fp8 path (Q: scale log2(e); K: 1.0), hi-split byte layout
      const float csc = (mode == 0) ? 1.44269504f : 1.0f;
      __syncthreads();
      uint8_t* ot8 = (uint8_t*)tile;  // [64 tok][64 B]
      #pragma unroll
      for (int jc = 0; jc < 4; ++jc) {
        #pragma unroll
        for (int r = 0; r < 4; ++r) {
          int row = wid * 16 + g * 4 + r;
          int pos = (jc >> 1) * 32 + (lr >> 3) * 16 + (jc & 1) * 8 + (lr & 7);
          ot8[row * 64 + pos] = to_fp8((acc[jc][r] + bjv[jc]) * csc);
        }
      }
      __syncthreads();
      uint8_t* dst8 = (mode == 0) ? qg8 : kg8;
      int row = tid >> 2, s = tid & 3;   // 64 rows x 4 x 16B
      *(u32x4*)(dst8 + (trow0 + row) * 256 + jstrip * 64 + s * 16) =
          *(const u32x4*)(ot8 + row * 64 + s * 16);
    } else {
      // V fp8, chunked slot layout (attn stages it as an identity copy)
      __syncthreads();
      uint8_t* ot8 = (uint8_t*)tile;  // [2 kvblk][128 slots][16B] = 4KB
      #pragma unroll
      for (int jc = 0; jc < 4; ++jc) {
        #pragma unroll
        for (int r = 0; r < 4; ++r) {
          int tok64 = wid * 16 + g * 4 + r;
          int kvblk = tok64 >> 5, kv = tok64 & 31;
          int dl = jc * 16 + lr;
          int sel = (kv >> 3) & 1;
          int pos = (kv & 7) + ((kv >> 4) & 1) * 8;
          int sloc = (dl >> 3) * 16 + sel * 8 + (dl & 7);
          ot8[kvblk * 2048 + sloc * 16 + pos] = to_fp8(acc[jc][r] + bjv[jc]);
        }
      }
      __syncthreads();
      int kvblk = tid >> 7, sl = tid & 127;
      size_t bb = trow0 >> 12;
      size_t nblk = ((trow0 & 4095) >> 5) + kvblk;
      *(u32x4*)(vt8 + ((bb * 128 + nblk) * 512 + jstrip * 128 + sl) * 16) =
          *(const u32x4*)(ot8 + kvblk * 2048 + sl * 16);
    }
    __syncthreads();
  }
}

// ---------------- flash attention v13: split-KV + full fp8 + 64kv per barrier
// R15 single change vs R14: TWO 32-kv sub-tiles per sync period (barrier count
// 64 -> 32, the per-iter vmcnt(0)-drain+barrier overhead halves; staged loads
// get ~2x the compute window to land). Inner math byte-identical to R14.
// LDS: K dbuf 2x16KB @0, V dbuf 2x16KB @32768 = 65536 B; 2 blocks/CU.
#define ATTN_LDS 65536

__global__ __launch_bounds__(256)
__attribute__((amdgpu_waves_per_eu(2, 2)))
void attn_kernel(
    const uint8_t* __restrict__ qg8, const uint8_t* __restrict__ kg8,
    const uint8_t* __restrict__ vt8, _Float16* __restrict__ po,
    float* __restrict__ mbuf, float* __restrict__ lbuf) {
  extern __shared__ char smem[];

  const int tid  = threadIdx.x;
  const int lane = tid & 63;
  const int wid  = tid >> 6;    // 0..3 = q-group
  const int l31  = lane & 31;
  const int hi   = lane >> 5;   // 0/1
  const int bid  = blockIdx.x;
  const int b    = bid & 7;               // XCD-affine batch
  const int kvh  = (bid >> 3) & 1;        // kv half
  const int n0   = (bid >> 4) * 128;      // q-tile base
  const int kvbase = kvh * 2048;

  // ---- prologue: stage 64-kv tile 0 (K fp8 16KB + V fp8 chunked 16KB) into buf 0
  #pragma unroll
  for (int i = 0; i < 4; ++i) {
    int slot = i * 256 + tid;             // 1024 slots each
    int row = slot >> 4, s = slot & 15;   // K: 64 rows x 16 slots
    gload_lds16(kg8 + ((size_t)(b * NSEQ + kvbase + row)) * 256 + ((s ^ (row & 7)) << 4),
                smem + slot * 16);
    gload_lds16(vt8 + ((size_t)(b * 128 + kvh * 64 + (slot >> 9)) * 512 + (slot & 511)) * 16,
                smem + 32768 + slot * 16);
  }

  // ---- Q fragments (fp8): lane holds Q[q=l31][c = m*16 + hi*8 + j], 8 B per frag
  long qf8[16];
  {
    const uint8_t* qp8 = qg8 + ((size_t)(b * NSEQ + n0 + wid * 32 + l31)) * 256;
    #pragma unroll
    for (int p = 0; p < 8; ++p) {
      u64x2 qq = *(const u64x2*)(qp8 + (2 * p + hi) * 16);
      qf8[2 * p]     = (long)qq.x;
      qf8[2 * p + 1] = (long)qq.y;
    }
  }

  f32x16 o[8];  // O[q=(r&3)+8*(r>>2)+4*hi][d=dt*32+l31], f32 (unnormalized)
  #pragma unroll
  for (int dt = 0; dt < 8; ++dt)
    #pragma unroll
    for (int r = 0; r < 16; ++r) o[dt][r] = 0.0f;
  float mrun = -1e30f, lrun = 0.0f;

  __syncthreads();  // prologue staging drained

  for (int t = 0; t < 32; ++t) {
    const int cur = t & 1;
    const char* kb = smem + cur * 16384;
    const char* vb = smem + 32768 + cur * 16384;

    // issue next 64-kv tile's staging into the other buffer
    if (t < 31) {
      const int kv0n = kvbase + (t + 1) * 64;
      char* kn = smem + (cur ^ 1) * 16384;
      char* vn = smem + 32768 + (cur ^ 1) * 16384;
      #pragma unroll
      for (int i = 0; i < 4; ++i) {
        int slot = i * 256 + tid;
        int row = slot >> 4, s = slot & 15;
        gload_lds16(kg8 + ((size_t)(b * NSEQ + kv0n + row)) * 256 + ((s ^ (row & 7)) << 4),
                    kn + slot * 16);
        gload_lds16(vt8 + ((size_t)(b * 128 + kvh * 64 + (t + 1) * 2 + (slot >> 9)) * 512 +
                           (slot & 511)) * 16,
                    vn + slot * 16);
      }
    }

    #pragma unroll
    for (int half = 0; half < 2; ++half) {
      const char* kbh = kb + half * 8192;   // 32 kv rows x 256B
      const char* vbh = vb + half * 8192;   // 512 slots x 16B

      // ---- S^T = K x Q^T (fp8): 16 MFMA, 8 LDS reads (b128 = 2 A-frags)
      f32x16 sacc;
      #pragma unroll
      for (int r = 0; r < 16; ++r) sacc[r] = 0.0f;
      const char* krowp = kbh + l31 * 256;
      #pragma unroll
      for (int p = 0; p < 8; ++p) {
        u64x2 kk = *(const u64x2*)(krowp + (((2 * p + hi) ^ (l31 & 7)) << 4));
        sacc = __builtin_amdgcn_mfma_f32_32x32x16_fp8_fp8((long)kk.x, qf8[2 * p],
                                                          sacc, 0, 0, 0);
        sacc = __builtin_amdgcn_mfma_f32_32x32x16_fp8_fp8((long)kk.y, qf8[2 * p + 1],
                                                          sacc, 0, 0, 0);
      }
      #pragma unroll
      for (int r = 0; r < 16; ++r) sacc[r] *= 0.0625f;  // attention scale 1/16

      // ---- in-register online softmax
      float pm = sacc[0];
      #pragma unroll
      for (int r = 1; r < 16; ++r) pm = fmaxf(pm, sacc[r]);
      pm = fmaxf(pm, sx32f(pm));  // full 32-kv row max for this tile

      if (!__all(pm - mrun <= 8.0f)) {   // defer-max (T13), THR=8 in log2 domain
        float mnew = fmaxf(mrun, pm);
        float al = exp2f(mrun - mnew);
        mrun = mnew;
        lrun *= al;
        #pragma unroll
        for (int r = 0; r < 16; ++r) {
          float ar = __shfl(al, (r & 3) + 8 * (r >> 2) + 4 * hi, 64);
          #pragma unroll
          for (int dt = 0; dt < 8; ++dt) o[dt][r] *= ar;
        }
      }

      // exp2 in place (sacc becomes P)
      float ls = 0.0f;
      #pragma unroll
      for (int r = 0; r < 16; ++r) { sacc[r] = exp2f(sacc[r] - mrun); ls += sacc[r]; }
      lrun += ls + sx32f(ls);

      // ---- pack P -> fp8 A-frags: 8 cvt_pk + 4 lane^32 shfl + select
      uint32_t w0 = pk4_fp8(sacc[0],  sacc[1],  sacc[2],  sacc[3]);
      uint32_t w1 = pk4_fp8(sacc[4],  sacc[5],  sacc[6],  sacc[7]);
      uint32_t w2 = pk4_fp8(sacc[8],  sacc[9],  sacc[10], sacc[11]);
      uint32_t w3 = pk4_fp8(sacc[12], sacc[13], sacc[14], sacc[15]);
      uint32_t t0 = sx32u(w0), t1 = sx32u(w1), t2 = sx32u(w2), t3 = sx32u(w3);
      long pa0 = (long)(((uint64_t)(hi ? w1 : t0) << 32) | (uint32_t)(hi ? t1 : w0));
      long pa1 = (long)(((uint64_t)(hi ? w3 : t2) << 32) | (uint32_t)(hi ? t3 : w2));

      // ---- PV: O += P x V (fp8): 16 MFMA, 8 LDS reads (b128 = both B-frags)
      #pragma unroll
      for (int dt = 0; dt < 8; ++dt) {
        const int dv = dt * 32 + l31;
        u64x2 vv = *(const u64x2*)(vbh + (dv >> 3) * 256 + hi * 128 + (dv & 7) * 16);
        o[dt] = __builtin_amdgcn_mfma_f32_32x32x16_fp8_fp8(pa0, (long)vv.x, o[dt], 0, 0, 0);
        o[dt] = __builtin_amdgcn_mfma_f32_32x32x16_fp8_fp8(pa1, (long)vv.y, o[dt], 0, 0, 0);
      }
    }

    __syncthreads();  // reads of buf[cur] done + staging into buf[cur^1] drained
  }

  // ---- epilogue: store unnormalized partials (merge kernel combines halves)
  const size_t tok0 = (size_t)b * NSEQ + n0 + wid * 32;
  if (lane < 32) {
    mbuf[(size_t)kvh * NTOK + tok0 + l31] = mrun;
    lbuf[(size_t)kvh * NTOK + tok0 + l31] = lrun;
  }
  #pragma unroll
  for (int r = 0; r < 16; ++r) {
    int q = (r & 3) + 8 * (r >> 2) + 4 * hi;
    _Float16* prow = po + ((size_t)kvh * NTOK + tok0 + q) * CDIM + l31;
    #pragma unroll
    for (int dt = 0; dt < 8; ++dt)
      prow[dt * 32] = (_Float16)o[dt][r];
  }
}

// ---------------- merge: combine the two kv-half partials per token
__global__ __launch_bounds__(256) void merge_kernel(
    const _Float16* __restrict__ po, const float* __restrict__ mbuf,
    const float* __restrict__ lbuf, _Float16* __restrict__ og) {
  const int lane = threadIdx.x & 63;
  const size_t tok = (size_t)blockIdx.x * 4 + (threadIdx.x >> 6);
  const float m0 = mbuf[tok], m1 = mbuf[NTOK + tok];
  const float l0 = lbuf[tok], l1 = lbuf[NTOK + tok];
  const float mm = fmaxf(m0, m1);
  const float a0 = exp2f(m0 - mm), a1 = exp2f(m1 - mm);
  const float rl = 1.0f / (l0 * a0 + l1 * a1);
  const half4v o0 = ((const half4v*)(po + tok * CDIM))[lane];
  const half4v o1 = ((const half4v*)(po + ((size_t)NTOK + tok) * CDIM))[lane];
  half4v out;
  #pragma unroll
  for (int j = 0; j < 4; ++j)
    out[j] = (_Float16)(((float)o0[j] * a0 + (float)o1[j] * a1) * rl);
  ((half4v*)(og + tok * CDIM))[lane] = out;
}

// ---------------- launcher
extern "C" void kernel_launch(void* const* d_in, const int* in_sizes, int n_in,
                              void* d_out, int out_size, void* d_ws, size_t ws_size,
                              hipStream_t stream) {
  const float* x   = (const float*)d_in[0];
  const float* gam = (const float*)d_in[1];
  const float* bet = (const float*)d_in[2];
  const float* wq  = (const float*)d_in[3];
  const float* bq  = (const float*)d_in[4];
  const float* wk  = (const float*)d_in[5];
  const float* bk  = (const float*)d_in[6];
  const float* wv  = (const float*)d_in[7];
  const float* bv  = (const float*)d_in[8];
  const float* wp  = (const float*)d_in[9];
  const float* bp  = (const float*)d_in[10];
  float* out = (float*)d_out;

  char* ws = (char*)d_ws;
  _Float16* po  = (_Float16*)ws;                          // 32MB partial O x2 halves
  _Float16* xnh = (_Float16*)(ws + (32u << 20));          // 16MB f16 xn
  uint8_t*  qh8 = (uint8_t*)(ws + (48u << 20));           //  8MB q fp8 (scaled)
  uint8_t*  kh8 = (uint8_t*)(ws + (56u << 20));           //  8MB k fp8
  uint8_t*  vt8 = (uint8_t*)(ws + (64u << 20));           //  8MB v fp8 chunked
  _Float16* oh  = (_Float16*)(ws + (72u << 20));          // 16MB attn out (merged)
  float*    mbf = (float*)(ws + (88u << 20));             // 256KB m x2 halves
  float*    lbf = (float*)(ws + (88u << 20) + (1u << 18)); // 256KB l x2 halves

  (void)hipFuncSetAttribute((const void*)proj_kernel,
                            hipFuncAttributeMaxDynamicSharedMemorySize, 65536);
  (void)hipFuncSetAttribute((const void*)attn_kernel,
                            hipFuncAttributeMaxDynamicSharedMemorySize, ATTN_LDS);

  ln_kernel<<<NTOK / 4, 256, 0, stream>>>(x, gam, bet, xnh);
  proj_kernel<<<dim3(64, 4, 3), 256, 65536, stream>>>(
      xnh, wq, bq, wk, bk, wv, bv, wp, bp, qh8, kh8, vt8, xnh, out, 0);
  attn_kernel<<<512, 256, ATTN_LDS, stream>>>(qh8, kh8, vt8, po, mbf, lbf);
  merge_kernel<<<NTOK / 4, 256, 0, stream>>>(po, mbf, lbf, oh);
  proj_kernel<<<dim3(64, 4, 1), 256, 65536, stream>>>(
      oh, wq, bq, wk, bk, wv, bv, wp, bp, qh8, kh8, vt8, xnh, out, 3);
}

// Round 18
// 193.716 us; speedup vs baseline: 1.0147x; 1.0147x over previous
//
#include <hip/hip_runtime.h>
#include <cstdint>

#define NB    8
#define NSEQ  4096
#define CDIM  256
#define NTOK  (NB*NSEQ)

typedef _Float16 half8  __attribute__((ext_vector_type(8)));
typedef _Float16 half4v __attribute__((ext_vector_type(4)));
typedef float    f32x4  __attribute__((ext_vector_type(4)));
typedef float    f32x16 __attribute__((ext_vector_type(16)));
typedef uint32_t u32x4  __attribute__((ext_vector_type(4)));
typedef unsigned long u64x2 __attribute__((ext_vector_type(2)));

typedef unsigned int u32_g __attribute__((address_space(1)));
typedef unsigned int u32_l __attribute__((address_space(3)));

// direct global->LDS, 16B per lane; LDS dest = wave-uniform base + lane*16
__device__ __forceinline__ void gload_lds16(const void* g, void* l) {
  __builtin_amdgcn_global_load_lds((u32_g*)(uintptr_t)g,
                                   (u32_l*)(uint32_t)(uintptr_t)l, 16, 0, 0);
}

__device__ __forceinline__ uint8_t to_fp8(float v) {
  return (uint8_t)(__builtin_amdgcn_cvt_pk_fp8_f32(v, v, 0, false) & 0xff);
}
// pack 4 floats -> 4 fp8 bytes in one u32
__device__ __forceinline__ uint32_t pk4_fp8(float a, float b, float c, float d) {
  uint32_t w = (uint32_t)__builtin_amdgcn_cvt_pk_fp8_f32(a, b, 0, false);
  return (uint32_t)__builtin_amdgcn_cvt_pk_fp8_f32(c, d, (int)w, true);
}
// lane^32 exchange via shfl. NOTE: v_permlane32_swap replacements were tried
// in R16/R17 and FAILED (absmax 0.18) despite on-paper-correct derivations --
// the instruction's swap direction is unverifiable here; shfl is semantics-
// certain (ds_bpermute). Do not retry permlane without a HW semantics probe.
__device__ __forceinline__ float sx32f(float v) { return __shfl_xor(v, 32, 64); }
__device__ __forceinline__ uint32_t sx32u(uint32_t v) {
  return (uint32_t)__shfl_xor((int)v, 32, 64);
}

// ---------------- LayerNorm: one wave per token; f16 xn only
__global__ __launch_bounds__(256) void ln_kernel(
    const float* __restrict__ x, const float* __restrict__ gam,
    const float* __restrict__ bet, _Float16* __restrict__ xnh) {
  const int lane = threadIdx.x & 63;
  const size_t tok = (size_t)blockIdx.x * 4 + (threadIdx.x >> 6);
  const float4 v = ((const float4*)(x + tok * CDIM))[lane];
  float s  = v.x + v.y + v.z + v.w;
  float s2 = v.x*v.x + v.y*v.y + v.z*v.z + v.w*v.w;
  #pragma unroll
  for (int m = 1; m < 64; m <<= 1) {
    s  += __shfl_xor(s,  m, 64);
    s2 += __shfl_xor(s2, m, 64);
  }
  const float mean = s * (1.0f / CDIM);
  const float rstd = rsqrtf(s2 * (1.0f / CDIM) - mean * mean + 1e-3f);
  const float4 gv = ((const float4*)gam)[lane];
  const float4 bv = ((const float4*)bet)[lane];
  half4v h;
  h[0] = (_Float16)((v.x - mean) * rstd * gv.x + bv.x);
  h[1] = (_Float16)((v.y - mean) * rstd * gv.y + bv.y);
  h[2] = (_Float16)((v.z - mean) * rstd * gv.z + bv.z);
  h[3] = (_Float16)((v.w - mean) * rstd * gv.w + bv.w);
  ((half4v*)(xnh + tok * CDIM))[lane] = h;
}

// ---------------- projection GEMM
// modes: 0=Q (fp8, log2e folded), 1=K (fp8), 2=V (fp8 chunked), 3=P (fp32+resid)
// Q/K fp8 rows hi-split: byte(m,hi,j) = (m>>1)*32 + hi*16 + (m&1)*8 + j.
// V chunk layout: slot(d,sel) = (d>>3)*16 + sel*8 + (d&7); chunk bytes:
//   sel=0 = [kv0-7 | kv16-23], sel=1 = [kv8-15 | kv24-31] (kv = token & 31).
__global__ __launch_bounds__(256, 2) void proj_kernel(
    const _Float16* __restrict__ inh,
    const float* __restrict__ wq_, const float* __restrict__ bq_,
    const float* __restrict__ wk_, const float* __restrict__ bk_,
    const float* __restrict__ wv_, const float* __restrict__ bv_,
    const float* __restrict__ wp_, const float* __restrict__ bp_,
    uint8_t* __restrict__ qg8, uint8_t* __restrict__ kg8,
    uint8_t* __restrict__ vt8,
    const _Float16* __restrict__ residh, float* __restrict__ outf,
    int mode_base) {
  extern __shared__ char smem[];
  const int mode = mode_base + blockIdx.z;
  const float* wsel = (mode == 0) ? wq_ : (mode == 1) ? wk_ : (mode == 2) ? wv_ : wp_;
  const float* bsel = (mode == 0) ? bq_ : (mode == 1) ? bk_ : (mode == 2) ? bv_ : bp_;

  const int tid = threadIdx.x;
  const int lane = tid & 63;
  const int wid  = tid >> 6;     // 0..3
  const int g    = lane >> 4;    // 0..3
  const int lr   = lane & 15;
  const int jstrip = blockIdx.y; // 0..3
  const size_t tok0 = (size_t)blockIdx.x * 512;

  char* wt   = smem;             // [64 j][256 c] f16, XOR-swizzled (32KB)
  char* tile = smem + 32768;     // [64 tok][256 c] f16, swizzled (32KB)

  // w-staging, float4-vectorized (R18: 16 vec loads vs 64 scalar loads)
  #pragma unroll
  for (int i = 0; i < 16; ++i) {
    int idx = i * 256 + tid;          // 4096 float4 groups: c=idx>>4, j4=idx&15
    int c = idx >> 4, j4 = idx & 15;
    float4 wv = *(const float4*)(wsel + (size_t)c * CDIM + jstrip * 64 + j4 * 4);
    #pragma unroll
    for (int e = 0; e < 4; ++e) {
      int j = j4 * 4 + e;
      float val = (e == 0) ? wv.x : (e == 1) ? wv.y : (e == 2) ? wv.z : wv.w;
      *(_Float16*)(wt + j * 512 + ((((c >> 3) ^ (j & 7))) << 4) + ((c & 7) << 1)) =
          (_Float16)val;
    }
  }
  float bjv[4];
  #pragma unroll
  for (int jc = 0; jc < 4; ++jc) bjv[jc] = bsel[jstrip * 64 + jc * 16 + lr];
  __syncthreads();

  for (int t = 0; t < 8; ++t) {
    const size_t trow0 = tok0 + t * 64;
    #pragma unroll
    for (int i = 0; i < 8; ++i) {
      int pbase = (i * 4 + wid) * 64;
      int p = pbase + lane;
      int row = p >> 5, sl = p & 31;
      gload_lds16(inh + (trow0 + row) * CDIM + (size_t)((sl ^ (row & 7)) * 8),
                  tile + pbase * 16);
    }
    __syncthreads();

    f32x4 acc[4] = {{0,0,0,0},{0,0,0,0},{0,0,0,0},{0,0,0,0}};
    #pragma unroll
    for (int kc = 0; kc < 8; ++kc) {
      half8 a = *(const half8*)(tile + (wid * 16 + lr) * 512 +
                                ((((kc << 2) | g) ^ (lr & 7)) << 4));
      #pragma unroll
      for (int jc = 0; jc < 4; ++jc) {
        half8 bf = *(const half8*)(wt + (jc * 16 + lr) * 512 +
                                   ((((kc << 2) | g) ^ (lr & 7)) << 4));
        acc[jc] = __builtin_amdgcn_mfma_f32_16x16x32_f16(a, bf, acc[jc], 0, 0, 0);
      }
    }

    if (mode == 3) {
      #pragma unroll
      for (int jc = 0; jc < 4; ++jc) {
        #pragma unroll
        for (int r = 0; r < 4; ++r) {
          size_t row = trow0 + wid * 16 + g * 4 + r;
          size_t off = row * CDIM + jstrip * 64 + jc * 16 + lr;
          outf[off] = acc[jc][r] + bjv[jc] + (float)residh[off];
        }
      }
    } else if (mode <= 1) {
      // fp8 path (Q: scale log2(e); K: 1.0), hi-split byte layout
      const float csc = (mode == 0) ? 1.44269504f : 1.0f;
      __syncthreads();
      uint8_t* ot8 = (uint8_t*)tile;  // [64 tok][64 B]
      #pragma unroll
      for (int jc = 0; jc < 4; ++jc) {
        #pragma unroll
        for (int r = 0; r < 4; ++r) {
          int row = wid * 16 + g * 4 + r;
          int pos = (jc >> 1) * 32 + (lr >> 3) * 16 + (jc & 1) * 8 + (lr & 7);
          ot8[row * 64 + pos] = to_fp8((acc[jc][r] + bjv[jc]) * csc);
        }
      }
      __syncthreads();
      uint8_t* dst8 = (mode == 0) ? qg8 : kg8;
      int row = tid >> 2, s = tid & 3;   // 64 rows x 4 x 16B
      *(u32x4*)(dst8 + (trow0 + row) * 256 + jstrip * 64 + s * 16) =
          *(const u32x4*)(ot8 + row * 64 + s * 16);
    } else {
      // V fp8, chunked slot layout (attn stages it as an identity copy)
      __syncthreads();
      uint8_t* ot8 = (uint8_t*)tile;  // [2 kvblk][128 slots][16B] = 4KB
      #pragma unroll
      for (int jc = 0; jc < 4; ++jc) {
        #pragma unroll
        for (int r = 0; r < 4; ++r) {
          int tok64 = wid * 16 + g * 4 + r;
          int kvblk = tok64 >> 5, kv = tok64 & 31;
          int dl = jc * 16 + lr;
          int sel = (kv >> 3) & 1;
          int pos = (kv & 7) + ((kv >> 4) & 1) * 8;
          int sloc = (dl >> 3) * 16 + sel * 8 + (dl & 7);
          ot8[kvblk * 2048 + sloc * 16 + pos] = to_fp8(acc[jc][r] + bjv[jc]);
        }
      }
      __syncthreads();
      int kvblk = tid >> 7, sl = tid & 127;
      size_t bb = trow0 >> 12;
      size_t nblk = ((trow0 & 4095) >> 5) + kvblk;
      *(u32x4*)(vt8 + ((bb * 128 + nblk) * 512 + jstrip * 128 + sl) * 16) =
          *(const u32x4*)(ot8 + kvblk * 2048 + sl * 16);
    }
    __syncthreads();
  }
}

// ---------------- flash attention v16 = R14-exact (verified 134.7us pass)
// + tree reductions only (pure reassociation). shfl lane^32 exchange and the
// R14-verified pack retained; permlane closed (R16/R17 evidence).
// LDS: K dbuf 2x8KB @0, V dbuf 2x8KB @16384 = 32768 B; 2 blocks/CU.
#define ATTN_LDS 32768

__global__ __launch_bounds__(256)
__attribute__((amdgpu_waves_per_eu(2, 2)))
void attn_kernel(
    const uint8_t* __restrict__ qg8, const uint8_t* __restrict__ kg8,
    const uint8_t* __restrict__ vt8, _Float16* __restrict__ po,
    float* __restrict__ mbuf, float* __restrict__ lbuf) {
  extern __shared__ char smem[];

  const int tid  = threadIdx.x;
  const int lane = tid & 63;
  const int wid  = tid >> 6;    // 0..3 = q-group
  const int l31  = lane & 31;
  const int hi   = lane >> 5;   // 0/1
  const int bid  = blockIdx.x;
  const int b    = bid & 7;               // XCD-affine batch
  const int kvh  = (bid >> 3) & 1;        // kv half
  const int n0   = (bid >> 4) * 128;      // q-tile base
  const int kvbase = kvh * 2048;

  // ---- prologue: stage tile 0 (K fp8 [32][256B] + V fp8 chunked 8KB) into buf 0
  #pragma unroll
  for (int i = 0; i < 2; ++i) {
    int slot = i * 256 + tid;
    int row = slot >> 4, s = slot & 15;
    gload_lds16(kg8 + ((size_t)(b * NSEQ + kvbase + row)) * 256 + ((s ^ (row & 7)) << 4),
                smem + slot * 16);
    gload_lds16(vt8 + ((size_t)(b * 128 + kvh * 64) * 512 + slot) * 16,
                smem + 16384 + slot * 16);
  }

  // ---- Q fragments (fp8): lane holds Q[q=l31][c = m*16 + hi*8 + j], 8 B per frag
  long qf8[16];
  {
    const uint8_t* qp8 = qg8 + ((size_t)(b * NSEQ + n0 + wid * 32 + l31)) * 256;
    #pragma unroll
    for (int p = 0; p < 8; ++p) {
      u64x2 qq = *(const u64x2*)(qp8 + (2 * p + hi) * 16);
      qf8[2 * p]     = (long)qq.x;
      qf8[2 * p + 1] = (long)qq.y;
    }
  }

  f32x16 o[8];  // O[q=(r&3)+8*(r>>2)+4*hi][d=dt*32+l31], f32 (unnormalized)
  #pragma unroll
  for (int dt = 0; dt < 8; ++dt)
    #pragma unroll
    for (int r = 0; r < 16; ++r) o[dt][r] = 0.0f;
  float mrun = -1e30f, lrun = 0.0f;

  __syncthreads();  // prologue staging drained

  for (int t = 0; t < 64; ++t) {
    const int cur = t & 1;
    const char* kb = smem + cur * 8192;
    const char* vb = smem + 16384 + cur * 8192;

    // issue next tile's staging into the other buffer
    if (t < 63) {
      const int kv0n = kvbase + (t + 1) * 32;
      char* kn = smem + (cur ^ 1) * 8192;
      char* vn = smem + 16384 + (cur ^ 1) * 8192;
      #pragma unroll
      for (int i = 0; i < 2; ++i) {
        int slot = i * 256 + tid;
        int row = slot >> 4, s = slot & 15;
        gload_lds16(kg8 + ((size_t)(b * NSEQ + kv0n + row)) * 256 + ((s ^ (row & 7)) << 4),
                    kn + slot * 16);
        gload_lds16(vt8 + ((size_t)(b * 128 + kvh * 64 + t + 1) * 512 + slot) * 16,
                    vn + slot * 16);
      }
    }

    // ---- S^T = K x Q^T (fp8): 16 MFMA, 8 LDS reads (b128 = 2 A-frags)
    f32x16 sacc;
    #pragma unroll
    for (int r = 0; r < 16; ++r) sacc[r] = 0.0f;
    const char* krowp = kb + l31 * 256;
    #pragma unroll
    for (int p = 0; p < 8; ++p) {
      u64x2 kk = *(const u64x2*)(krowp + (((2 * p + hi) ^ (l31 & 7)) << 4));
      sacc = __builtin_amdgcn_mfma_f32_32x32x16_fp8_fp8((long)kk.x, qf8[2 * p],
                                                        sacc, 0, 0, 0);
      sacc = __builtin_amdgcn_mfma_f32_32x32x16_fp8_fp8((long)kk.y, qf8[2 * p + 1],
                                                        sacc, 0, 0, 0);
    }
    #pragma unroll
    for (int r = 0; r < 16; ++r) sacc[r] *= 0.0625f;  // attention scale 1/16

    // ---- in-register online softmax; tree max (safe reassociation)
    float m01 = fmaxf(fmaxf(sacc[0], sacc[1]),  fmaxf(sacc[2],  sacc[3]));
    float m23 = fmaxf(fmaxf(sacc[4], sacc[5]),  fmaxf(sacc[6],  sacc[7]));
    float m45 = fmaxf(fmaxf(sacc[8], sacc[9]),  fmaxf(sacc[10], sacc[11]));
    float m67 = fmaxf(fmaxf(sacc[12], sacc[13]),fmaxf(sacc[14], sacc[15]));
    float pm = fmaxf(fmaxf(m01, m23), fmaxf(m45, m67));
    pm = fmaxf(pm, sx32f(pm));  // full 32-kv row max for this tile

    if (!__all(pm - mrun <= 8.0f)) {   // defer-max (T13), THR=8 in log2 domain
      float mnew = fmaxf(mrun, pm);
      float al = exp2f(mrun - mnew);
      mrun = mnew;
      lrun *= al;
      #pragma unroll
      for (int r = 0; r < 16; ++r) {
        float ar = __shfl(al, (r & 3) + 8 * (r >> 2) + 4 * hi, 64);
        #pragma unroll
        for (int dt = 0; dt < 8; ++dt) o[dt][r] *= ar;
      }
    }

    // exp2 in place (sacc becomes P); tree sum
    #pragma unroll
    for (int r = 0; r < 16; ++r) sacc[r] = exp2f(sacc[r] - mrun);
    float s01 = (sacc[0] + sacc[1])   + (sacc[2]  + sacc[3]);
    float s23 = (sacc[4] + sacc[5])   + (sacc[6]  + sacc[7]);
    float s45 = (sacc[8] + sacc[9])   + (sacc[10] + sacc[11]);
    float s67 = (sacc[12] + sacc[13]) + (sacc[14] + sacc[15]);
    float ls  = (s01 + s23) + (s45 + s67);
    lrun += ls + sx32f(ls);

    // ---- pack P -> fp8 A-frags: 8 cvt_pk + 4 lane^32 shfl + select (R14-verified)
    uint32_t w0 = pk4_fp8(sacc[0],  sacc[1],  sacc[2],  sacc[3]);
    uint32_t w1 = pk4_fp8(sacc[4],  sacc[5],  sacc[6],  sacc[7]);
    uint32_t w2 = pk4_fp8(sacc[8],  sacc[9],  sacc[10], sacc[11]);
    uint32_t w3 = pk4_fp8(sacc[12], sacc[13], sacc[14], sacc[15]);
    uint32_t t0 = sx32u(w0), t1 = sx32u(w1), t2 = sx32u(w2), t3 = sx32u(w3);
    long pa0 = (long)(((uint64_t)(hi ? w1 : t0) << 32) | (uint32_t)(hi ? t1 : w0));
    long pa1 = (long)(((uint64_t)(hi ? w3 : t2) << 32) | (uint32_t)(hi ? t3 : w2));

    // ---- PV: O += P x V (fp8): 16 MFMA, 8 LDS reads (b128 = both B-frags)
    #pragma unroll
    for (int dt = 0; dt < 8; ++dt) {
      const int dv = dt * 32 + l31;
      u64x2 vv = *(const u64x2*)(vb + (dv >> 3) * 256 + hi * 128 + (dv & 7) * 16);
      o[dt] = __builtin_amdgcn_mfma_f32_32x32x16_fp8_fp8(pa0, (long)vv.x, o[dt], 0, 0, 0);
      o[dt] = __builtin_amdgcn_mfma_f32_32x32x16_fp8_fp8(pa1, (long)vv.y, o[dt], 0, 0, 0);
    }

    __syncthreads();  // reads of buf[cur] done + staging into buf[cur^1] drained
  }

  // ---- epilogue: store unnormalized partials (merge kernel combines halves)
  const size_t tok0 = (size_t)b * NSEQ + n0 + wid * 32;
  if (lane < 32) {
    mbuf[(size_t)kvh * NTOK + tok0 + l31] = mrun;
    lbuf[(size_t)kvh * NTOK + tok0 + l31] = lrun;
  }
  #pragma unroll
  for (int r = 0; r < 16; ++r) {
    int q = (r & 3) + 8 * (r >> 2) + 4 * hi;
    _Float16* prow = po + ((size_t)kvh * NTOK + tok0 + q) * CDIM + l31;
    #pragma unroll
    for (int dt = 0; dt < 8; ++dt)
      prow[dt * 32] = (_Float16)o[dt][r];
  }
}

// ---------------- merge: combine the two kv-half partials per token
__global__ __launch_bounds__(256) void merge_kernel(
    const _Float16* __restrict__ po, const float* __restrict__ mbuf,
    const float* __restrict__ lbuf, _Float16* __restrict__ og) {
  const int lane = threadIdx.x & 63;
  const size_t tok = (size_t)blockIdx.x * 4 + (threadIdx.x >> 6);
  const float m0 = mbuf[tok], m1 = mbuf[NTOK + tok];
  const float l0 = lbuf[tok], l1 = lbuf[NTOK + tok];
  const float mm = fmaxf(m0, m1);
  const float a0 = exp2f(m0 - mm), a1 = exp2f(m1 - mm);
  const float rl = 1.0f / (l0 * a0 + l1 * a1);
  const half4v o0 = ((const half4v*)(po + tok * CDIM))[lane];
  const half4v o1 = ((const half4v*)(po + ((size_t)NTOK + tok) * CDIM))[lane];
  half4v out;
  #pragma unroll
  for (int j = 0; j < 4; ++j)
    out[j] = (_Float16)(((float)o0[j] * a0 + (float)o1[j] * a1) * rl);
  ((half4v*)(og + tok * CDIM))[lane] = out;
}

// ---------------- launcher
extern "C" void kernel_launch(void* const* d_in, const int* in_sizes, int n_in,
                              void* d_out, int out_size, void* d_ws, size_t ws_size,
                              hipStream_t stream) {
  const float* x   = (const float*)d_in[0];
  const float* gam = (const float*)d_in[1];
  const float* bet = (const float*)d_in[2];
  const float* wq  = (const float*)d_in[3];
  const float* bq  = (const float*)d_in[4];
  const float* wk  = (const float*)d_in[5];
  const float* bk  = (const float*)d_in[6];
  const float* wv  = (const float*)d_in[7];
  const float* bv  = (const float*)d_in[8];
  const float* wp  = (const float*)d_in[9];
  const float* bp  = (const float*)d_in[10];
  float* out = (float*)d_out;

  char* ws = (char*)d_ws;
  _Float16* po  = (_Float16*)ws;                          // 32MB partial O x2 halves
  _Float16* xnh = (_Float16*)(ws + (32u << 20));          // 16MB f16 xn
  uint8_t*  qh8 = (uint8_t*)(ws + (48u << 20));           //  8MB q fp8 (scaled)
  uint8_t*  kh8 = (uint8_t*)(ws + (56u << 20));           //  8MB k fp8
  uint8_t*  vt8 = (uint8_t*)(ws + (64u << 20));           //  8MB v fp8 chunked
  _Float16* oh  = (_Float16*)(ws + (72u << 20));          // 16MB attn out (merged)
  float*    mbf = (float*)(ws + (88u << 20));             // 256KB m x2 halves
  float*    lbf = (float*)(ws + (88u << 20) + (1u << 18)); // 256KB l x2 halves

  (void)hipFuncSetAttribute((const void*)proj_kernel,
                            hipFuncAttributeMaxDynamicSharedMemorySize, 65536);
  (void)hipFuncSetAttribute((const void*)attn_kernel,
                            hipFuncAttributeMaxDynamicSharedMemorySize, ATTN_LDS);

  ln_kernel<<<NTOK / 4, 256, 0, stream>>>(x, gam, bet, xnh);
  proj_kernel<<<dim3(64, 4, 3), 256, 65536, stream>>>(
      xnh, wq, bq, wk, bk, wv, bv, wp, bp, qh8, kh8, vt8, xnh, out, 0);
  attn_kernel<<<512, 256, ATTN_LDS, stream>>>(qh8, kh8, vt8, po, mbf, lbf);
  merge_kernel<<<NTOK / 4, 256, 0, stream>>>(po, mbf, lbf, oh);
  proj_kernel<<<dim3(64, 4, 1), 256, 65536, stream>>>(
      oh, wq, bq, wk, bk, wv, bv, wp, bp, qh8, kh8, vt8, xnh, out, 3);
}